// Round 1
// baseline (114.698 us; speedup 1.0000x reference)
//
#include <hip/hip_runtime.h>

#define NB   8
#define CIN  32
#define HH   28
#define WW   28
#define OC   64
#define HWSZ (HH*WW)            // 784
#define TOTAL (NB*OC*HWSZ)      // 401408
#define CNT  (NB*HWSZ)          // 6272 elements per channel for BN stats

// x strip in LDS: 32 channels x 4 rows x 30 cols (cols = WW+2 for padding)
#define TROWS 4
#define TCOLS 30
#define TSZ   (CIN*TROWS*TCOLS) // 3840 floats

__global__ __launch_bounds__(256) void adder_kernel(
    const float* __restrict__ x, const float* __restrict__ Wt,
    float* __restrict__ raw, double* __restrict__ stats)
{
    __shared__ float xs[TSZ];
    const int t   = threadIdx.x;
    const int bid = blockIdx.x;          // 224 blocks: n(8) x rowpair(14) x chalf(2)
    const int chalf = bid & 1;
    const int rp    = (bid >> 1) % 14;
    const int n     = bid / 28;
    const int h0    = rp * 2;

    // ---- stage x strip (rows h0-1 .. h0+2, cols -1..28) with zero padding ----
    for (int i = t; i < TSZ; i += 256) {
        int c   = i / (TROWS*TCOLS);
        int rem = i % (TROWS*TCOLS);
        int r   = rem / TCOLS;
        int col = rem % TCOLS;
        int hh  = h0 - 1 + r;
        int ww  = col - 1;
        float v = 0.0f;
        if (hh >= 0 && hh < HH && ww >= 0 && ww < WW)
            v = x[((n*CIN + c)*HH + hh)*WW + ww];
        xs[i] = v;
    }
    __syncthreads();

    const int lane  = t & 63;
    const int g     = __builtin_amdgcn_readfirstlane(t >> 6); // wave id, forced uniform
    const bool valid = lane < 56;                // 2 rows x 28 cols = 56 pixels
    const int p     = valid ? lane : 0;
    const int pr    = p / WW;                    // 0..1 row within strip
    const int pw    = p % WW;                    // 0..27 col
    const int o_base = chalf*32 + g*8;           // 8 channels per wave

    float acc[8];
    #pragma unroll
    for (int oo = 0; oo < 8; ++oo) acc[oo] = 0.0f;

    // current 3x3 patch in registers, prefetch next channel's patch
    float xr[9];
    {
        int b0 = pr*TCOLS + pw;   // c = 0
        #pragma unroll
        for (int dr = 0; dr < 3; ++dr)
            #pragma unroll
            for (int dc = 0; dc < 3; ++dc)
                xr[dr*3+dc] = xs[b0 + dr*TCOLS + dc];
    }

    for (int c = 0; c < CIN; ++c) {
        float xn[9];
        if (c + 1 < CIN) {
            int b2 = ((c+1)*TROWS + pr)*TCOLS + pw;
            #pragma unroll
            for (int dr = 0; dr < 3; ++dr)
                #pragma unroll
                for (int dc = 0; dc < 3; ++dc)
                    xn[dr*3+dc] = xs[b2 + dr*TCOLS + dc];
        }
        #pragma unroll
        for (int oo = 0; oo < 8; ++oo) {
            // o_base, oo, c all wave-uniform -> scalar loads (SGPRs)
            const float* wp = Wt + ((o_base + oo)*CIN + c)*9;
            #pragma unroll
            for (int j = 0; j < 9; ++j)
                acc[oo] += __builtin_fabsf(xr[j] - wp[j]);
        }
        if (c + 1 < CIN) {
            #pragma unroll
            for (int j = 0; j < 9; ++j) xr[j] = xn[j];
        }
    }

    // ---- write raw output and accumulate BN stats ----
    #pragma unroll
    for (int oo = 0; oo < 8; ++oo) {
        float val = valid ? -acc[oo] : 0.0f;
        if (valid)
            raw[((n*OC + o_base + oo)*HH + (h0 + pr))*WW + pw] = val;
        float s  = val;
        float s2 = val * val;
        #pragma unroll
        for (int off = 32; off >= 1; off >>= 1) {
            s  += __shfl_xor(s,  off, 64);
            s2 += __shfl_xor(s2, off, 64);
        }
        if (lane == 0) {
            atomicAdd(&stats[o_base + oo],      (double)s);
            atomicAdd(&stats[64 + o_base + oo], (double)s2);
        }
    }
}

__global__ __launch_bounds__(256) void bn_kernel(
    const float* __restrict__ raw, const double* __restrict__ stats,
    const float* __restrict__ gamma, const float* __restrict__ beta,
    float* __restrict__ out)
{
    int idx = blockIdx.x * 256 + threadIdx.x;
    if (idx >= TOTAL) return;
    int o = (idx / HWSZ) & (OC - 1);
    double mean = stats[o] * (1.0 / CNT);
    double var  = stats[64 + o] * (1.0 / CNT) - mean * mean;
    float inv   = (float)(1.0 / sqrt(var + 1e-5));
    float m     = (float)mean;
    out[idx] = (raw[idx] - m) * inv * gamma[o] + beta[o];
}

extern "C" void kernel_launch(void* const* d_in, const int* in_sizes, int n_in,
                              void* d_out, int out_size, void* d_ws, size_t ws_size,
                              hipStream_t stream) {
    const float* x     = (const float*)d_in[0];
    const float* Wt    = (const float*)d_in[1];
    const float* gamma = (const float*)d_in[2];
    const float* beta  = (const float*)d_in[3];
    float* out = (float*)d_out;

    // ws layout: [0,1024) = 128 doubles of BN stats (sum, sumsq); then raw fp32 buffer
    double* stats = (double*)d_ws;
    float*  raw   = (float*)((char*)d_ws + 1024);

    hipMemsetAsync(d_ws, 0, 1024, stream);  // zero stats (ws is poisoned each call)

    adder_kernel<<<NB * 14 * 2, 256, 0, stream>>>(x, Wt, raw, stats);
    bn_kernel<<<(TOTAL + 255) / 256, 256, 0, stream>>>(raw, stats, gamma, beta, out);
}

// Round 2
// 99.874 us; speedup vs baseline: 1.1484x; 1.1484x over previous
//
#include <hip/hip_runtime.h>

#define NB   8
#define CIN  32
#define HH   28
#define WW   28
#define OC   64
#define HWSZ (HH*WW)            // 784
#define TOTAL (NB*OC*HWSZ)      // 401408
#define CNT  (NB*HWSZ)          // 6272 elements per channel for BN stats

// x strip in LDS: 32 channels x 4 rows x 30 cols (cols = WW+2 for padding)
#define TROWS 4
#define TCOLS 30
#define TSZ   (CIN*TROWS*TCOLS) // 3840 floats

#define CPW 2                   // channels per wave -> 4 waves * 2 = 8 ch/block
#define CHGRPS 8                // 64 / 8 channel groups
#define GRID1 (NB*14*CHGRPS)    // 896 blocks

__global__ __launch_bounds__(256) void adder_kernel(
    const float* __restrict__ x, const float* __restrict__ Wt,
    float* __restrict__ raw, double* __restrict__ stats)
{
    __shared__ float xs[TSZ];
    const int t   = threadIdx.x;
    const int bid = blockIdx.x;          // 896 blocks: n(8) x rowpair(14) x chgrp(8)
    const int chgrp = bid & 7;
    const int rest  = bid >> 3;
    const int rp    = rest % 14;
    const int n     = rest / 14;
    const int h0    = rp * 2;

    // ---- stage x strip (rows h0-1 .. h0+2, cols -1..28) with zero padding ----
    for (int i = t; i < TSZ; i += 256) {
        int c   = i / (TROWS*TCOLS);
        int rem = i % (TROWS*TCOLS);
        int r   = rem / TCOLS;
        int col = rem % TCOLS;
        int hh  = h0 - 1 + r;
        int ww  = col - 1;
        float v = 0.0f;
        if (hh >= 0 && hh < HH && ww >= 0 && ww < WW)
            v = x[((n*CIN + c)*HH + hh)*WW + ww];
        xs[i] = v;
    }
    __syncthreads();

    const int lane  = t & 63;
    const int g     = __builtin_amdgcn_readfirstlane(t >> 6); // wave id, uniform
    const bool valid = lane < 56;                // 2 rows x 28 cols
    const int p     = valid ? lane : 0;
    const int pr    = p / WW;
    const int pw    = p % WW;
    const int o_base = chgrp*8 + g*CPW;          // 2 channels per wave

    float acc[CPW];
    #pragma unroll
    for (int oo = 0; oo < CPW; ++oo) acc[oo] = 0.0f;

    // current 3x3 patch in registers, prefetch next channel's patch
    float xr[9];
    {
        int b0 = pr*TCOLS + pw;   // c = 0
        #pragma unroll
        for (int dr = 0; dr < 3; ++dr)
            #pragma unroll
            for (int dc = 0; dc < 3; ++dc)
                xr[dr*3+dc] = xs[b0 + dr*TCOLS + dc];
    }

    for (int c = 0; c < CIN; ++c) {
        float xn[9];
        if (c + 1 < CIN) {
            int b2 = ((c+1)*TROWS + pr)*TCOLS + pw;
            #pragma unroll
            for (int dr = 0; dr < 3; ++dr)
                #pragma unroll
                for (int dc = 0; dc < 3; ++dc)
                    xn[dr*3+dc] = xs[b2 + dr*TCOLS + dc];
        }
        #pragma unroll
        for (int oo = 0; oo < CPW; ++oo) {
            // o_base, oo, c all wave-uniform -> scalar loads (SGPRs)
            const float* wp = Wt + ((o_base + oo)*CIN + c)*9;
            #pragma unroll
            for (int j = 0; j < 9; ++j)
                acc[oo] += __builtin_fabsf(xr[j] - wp[j]);
        }
        if (c + 1 < CIN) {
            #pragma unroll
            for (int j = 0; j < 9; ++j) xr[j] = xn[j];
        }
    }

    // ---- write raw output and accumulate BN stats ----
    #pragma unroll
    for (int oo = 0; oo < CPW; ++oo) {
        float val = valid ? -acc[oo] : 0.0f;
        if (valid)
            raw[((n*OC + o_base + oo)*HH + (h0 + pr))*WW + pw] = val;
        float s  = val;
        float s2 = val * val;
        #pragma unroll
        for (int off = 32; off >= 1; off >>= 1) {
            s  += __shfl_xor(s,  off, 64);
            s2 += __shfl_xor(s2, off, 64);
        }
        if (lane == 0) {
            atomicAdd(&stats[o_base + oo],      (double)s);
            atomicAdd(&stats[64 + o_base + oo], (double)s2);
        }
    }
}

// per-channel scale/shift: sc[o] = gamma*rsqrt(var+eps); sc[64+o] = beta - mean*sc[o]
__global__ __launch_bounds__(64) void bn_prep(
    const double* __restrict__ stats,
    const float* __restrict__ gamma, const float* __restrict__ beta,
    float* __restrict__ sc)
{
    int o = threadIdx.x;
    double mean = stats[o] * (1.0 / CNT);
    double var  = stats[64 + o] * (1.0 / CNT) - mean * mean;
    double inv  = 1.0 / sqrt(var + 1e-5);
    double s    = (double)gamma[o] * inv;
    sc[o]       = (float)s;
    sc[64 + o]  = (float)((double)beta[o] - mean * s);
}

// y = raw*sc[o] + sh[o], float4-vectorized (HWSZ%4==0 so o uniform per float4)
__global__ __launch_bounds__(256) void bn_kernel(
    const float* __restrict__ raw, const float* __restrict__ sc,
    float* __restrict__ out)
{
    int i4 = blockIdx.x * 256 + threadIdx.x;   // float4 index
    if (i4 >= TOTAL/4) return;
    int o = (i4 / (HWSZ/4)) & (OC - 1);
    float s = sc[o];
    float b = sc[64 + o];
    float4 v = ((const float4*)raw)[i4];
    v.x = v.x * s + b;
    v.y = v.y * s + b;
    v.z = v.z * s + b;
    v.w = v.w * s + b;
    ((float4*)out)[i4] = v;
}

extern "C" void kernel_launch(void* const* d_in, const int* in_sizes, int n_in,
                              void* d_out, int out_size, void* d_ws, size_t ws_size,
                              hipStream_t stream) {
    const float* x     = (const float*)d_in[0];
    const float* Wt    = (const float*)d_in[1];
    const float* gamma = (const float*)d_in[2];
    const float* beta  = (const float*)d_in[3];
    float* out = (float*)d_out;

    // ws layout: [0,1024) stats (128 doubles); [1024,1536) sc (128 floats); [2048,...) raw
    double* stats = (double*)d_ws;
    float*  sc    = (float*)((char*)d_ws + 1024);
    float*  raw   = (float*)((char*)d_ws + 2048);

    hipMemsetAsync(d_ws, 0, 1024, stream);  // zero stats only

    adder_kernel<<<GRID1, 256, 0, stream>>>(x, Wt, raw, stats);
    bn_prep<<<1, 64, 0, stream>>>(stats, gamma, beta, sc);
    bn_kernel<<<(TOTAL/4 + 255) / 256, 256, 0, stream>>>(raw, sc, out);
}

// Round 3
// 78.754 us; speedup vs baseline: 1.4564x; 1.2682x over previous
//
#include <hip/hip_runtime.h>

#define NB   8
#define CIN  32
#define HH   28
#define WW   28
#define OC   64
#define HWSZ (HH*WW)            // 784
#define TOTAL (NB*OC*HWSZ)      // 401408
#define CNT  (NB*HWSZ)          // 6272 elements per channel for BN stats

#define KH   16                 // input channels per k-half
#define TROWS 4
#define TCOLS 30
#define TSZ  (KH*TROWS*TCOLS)   // 1920 floats = 7.7 KB LDS

#define CPW  2                  // output channels per wave (4 waves -> 8 ch/block)
// grid: n(8) x rowpair(14) x chgrp(8) x khalf(2) = 1792 blocks

__global__ __launch_bounds__(256) void adder_kernel(
    const float* __restrict__ x, const float* __restrict__ Wt,
    float* __restrict__ raw01)   // raw01 = two TOTAL-sized partial buffers
{
    __shared__ float xs[TSZ];
    const int t     = threadIdx.x;
    const int bid   = blockIdx.x;
    const int khalf = bid & 1;
    const int chgrp = (bid >> 1) & 7;
    const int rp    = (bid >> 4) % 14;
    const int n     = bid / (16 * 14);
    const int h0    = rp * 2;
    const int c0    = khalf * KH;

    // ---- stage x strip for channels c0..c0+15, rows h0-1..h0+2, cols -1..28 ----
    for (int i = t; i < TSZ; i += 256) {
        int cc  = i / (TROWS*TCOLS);
        int rem = i % (TROWS*TCOLS);
        int r   = rem / TCOLS;
        int col = rem % TCOLS;
        int hh  = h0 - 1 + r;
        int ww  = col - 1;
        float v = 0.0f;
        if (hh >= 0 && hh < HH && ww >= 0 && ww < WW)
            v = x[((n*CIN + (c0+cc))*HH + hh)*WW + ww];
        xs[i] = v;
    }
    __syncthreads();

    const int lane  = t & 63;
    const int g     = __builtin_amdgcn_readfirstlane(t >> 6); // wave id, uniform
    const bool valid = lane < 56;                 // 2 rows x 28 cols
    const int p     = valid ? lane : 0;
    const int pr    = p / WW;
    const int pw    = p % WW;
    const int o_base = chgrp*8 + g*CPW;

    float acc[CPW];
    #pragma unroll
    for (int oo = 0; oo < CPW; ++oo) acc[oo] = 0.0f;

    // current 3x3 patch in registers, prefetch next channel's patch
    float xr[9];
    {
        int b0 = pr*TCOLS + pw;   // cc = 0
        #pragma unroll
        for (int dr = 0; dr < 3; ++dr)
            #pragma unroll
            for (int dc = 0; dc < 3; ++dc)
                xr[dr*3+dc] = xs[b0 + dr*TCOLS + dc];
    }

    for (int cc = 0; cc < KH; ++cc) {
        float xn[9];
        if (cc + 1 < KH) {
            int b2 = ((cc+1)*TROWS + pr)*TCOLS + pw;
            #pragma unroll
            for (int dr = 0; dr < 3; ++dr)
                #pragma unroll
                for (int dc = 0; dc < 3; ++dc)
                    xn[dr*3+dc] = xs[b2 + dr*TCOLS + dc];
        }
        #pragma unroll
        for (int oo = 0; oo < CPW; ++oo) {
            const float* wp = Wt + ((o_base + oo)*CIN + (c0 + cc))*9; // uniform -> s_load
            #pragma unroll
            for (int j = 0; j < 9; ++j)
                acc[oo] += __builtin_fabsf(xr[j] - wp[j]);
        }
        if (cc + 1 < KH) {
            #pragma unroll
            for (int j = 0; j < 9; ++j) xr[j] = xn[j];
        }
    }

    // ---- write partial sums (negated at BN stage is wrong -- negate here) ----
    if (valid) {
        float* rawh = raw01 + khalf * TOTAL;
        #pragma unroll
        for (int oo = 0; oo < CPW; ++oo)
            rawh[((n*OC + o_base + oo)*HH + (h0 + pr))*WW + pw] = -acc[oo];
    }
}

// one block per output channel: combine halves, reduce sum/sumsq (double),
// emit per-channel scale/shift
__global__ __launch_bounds__(256) void stats_kernel(
    const float* __restrict__ raw01,
    const float* __restrict__ gamma, const float* __restrict__ beta,
    float* __restrict__ sc)
{
    const int o = blockIdx.x;
    const int t = threadIdx.x;
    const float4* r0 = (const float4*)raw01;
    const float4* r1 = (const float4*)(raw01 + TOTAL);
    double s = 0.0, s2 = 0.0;
    for (int i4 = t; i4 < CNT/4; i4 += 256) {     // 1568 float4s per channel
        int nn  = i4 / (HWSZ/4);
        int pos = i4 % (HWSZ/4);
        int idx = (nn*OC + o)*(HWSZ/4) + pos;
        float4 a = r0[idx];
        float4 b = r1[idx];
        float vx = a.x + b.x, vy = a.y + b.y, vz = a.z + b.z, vw = a.w + b.w;
        s  += (double)vx + (double)vy + (double)vz + (double)vw;
        s2 += (double)vx*vx + (double)vy*vy + (double)vz*vz + (double)vw*vw;
    }
    #pragma unroll
    for (int off = 32; off >= 1; off >>= 1) {
        s  += __shfl_xor(s,  off, 64);
        s2 += __shfl_xor(s2, off, 64);
    }
    __shared__ double ls[4], ls2[4];
    const int lane = t & 63, w = t >> 6;
    if (lane == 0) { ls[w] = s; ls2[w] = s2; }
    __syncthreads();
    if (t == 0) {
        double S  = ls[0] + ls[1] + ls[2] + ls[3];
        double S2 = ls2[0] + ls2[1] + ls2[2] + ls2[3];
        double mean = S * (1.0 / CNT);
        double var  = S2 * (1.0 / CNT) - mean * mean;
        double inv  = 1.0 / sqrt(var + 1e-5);
        double scl  = (double)gamma[o] * inv;
        sc[o]       = (float)scl;
        sc[64 + o]  = (float)((double)beta[o] - mean * scl);
    }
}

// y = (r0+r1)*sc[o] + sh[o], float4-vectorized
__global__ __launch_bounds__(256) void bn_kernel(
    const float* __restrict__ raw01, const float* __restrict__ sc,
    float* __restrict__ out)
{
    int i4 = blockIdx.x * 256 + threadIdx.x;   // float4 index
    if (i4 >= TOTAL/4) return;
    int o = (i4 / (HWSZ/4)) & (OC - 1);
    float s = sc[o];
    float b = sc[64 + o];
    float4 a0 = ((const float4*)raw01)[i4];
    float4 a1 = ((const float4*)(raw01 + TOTAL))[i4];
    float4 v;
    v.x = (a0.x + a1.x) * s + b;
    v.y = (a0.y + a1.y) * s + b;
    v.z = (a0.z + a1.z) * s + b;
    v.w = (a0.w + a1.w) * s + b;
    ((float4*)out)[i4] = v;
}

extern "C" void kernel_launch(void* const* d_in, const int* in_sizes, int n_in,
                              void* d_out, int out_size, void* d_ws, size_t ws_size,
                              hipStream_t stream) {
    const float* x     = (const float*)d_in[0];
    const float* Wt    = (const float*)d_in[1];
    const float* gamma = (const float*)d_in[2];
    const float* beta  = (const float*)d_in[3];
    float* out = (float*)d_out;

    // ws layout: [0,512) sc (128 floats); [4096, 4096+2*TOTAL*4) raw halves
    float* sc    = (float*)d_ws;
    float* raw01 = (float*)((char*)d_ws + 4096);

    adder_kernel<<<NB*14*8*2, 256, 0, stream>>>(x, Wt, raw01);
    stats_kernel<<<OC, 256, 0, stream>>>(raw01, gamma, beta, sc);
    bn_kernel<<<(TOTAL/4 + 255) / 256, 256, 0, stream>>>(raw01, sc, out);
}